// Round 11
// baseline (45.223 us; speedup 1.0000x reference)
//
#include <hip/hip_runtime.h>
#include <math.h>

#define EPSf 1e-12f

typedef float v2f __attribute__((ext_vector_type(2)));
typedef float f32x4 __attribute__((ext_vector_type(4)));
typedef _Float16 f16x8 __attribute__((ext_vector_type(8)));

__device__ __forceinline__ v2f mkv2(float a, float b) { v2f r; r.x = a; r.y = b; return r; }

// ---- forced VOP3P packed-f32 ops ----
// NOTE: gfx950 has NO v_pk_max_f32 / v_pk_min_f32 — only fma/mul/add/mov (R9 lesson).
__device__ __forceinline__ v2f pk_fma(v2f a, v2f b, v2f c) {
  v2f d; asm("v_pk_fma_f32 %0, %1, %2, %3" : "=v"(d) : "v"(a), "v"(b), "v"(c)); return d;
}
__device__ __forceinline__ v2f pk_mul(v2f a, v2f b) {
  v2f d; asm("v_pk_mul_f32 %0, %1, %2" : "=v"(d) : "v"(a), "v"(b)); return d;
}
__device__ __forceinline__ v2f v2max(v2f a, v2f b) { return __builtin_elementwise_max(a, b); }
// broadcast-lo / broadcast-hi of S0 via op_sel (free scalar*vector)
__device__ __forceinline__ v2f pk_fma_bl(v2f a, v2f b, v2f c) {
  v2f d; asm("v_pk_fma_f32 %0, %1, %2, %3 op_sel:[0,0,0] op_sel_hi:[0,1,1]"
             : "=v"(d) : "v"(a), "v"(b), "v"(c)); return d;
}
__device__ __forceinline__ v2f pk_fma_bh(v2f a, v2f b, v2f c) {
  v2f d; asm("v_pk_fma_f32 %0, %1, %2, %3 op_sel:[1,0,0] op_sel_hi:[1,1,1]"
             : "=v"(d) : "v"(a), "v"(b), "v"(c)); return d;
}
__device__ __forceinline__ v2f pk_mul_bl(v2f a, v2f b) {
  v2f d; asm("v_pk_mul_f32 %0, %1, %2 op_sel:[0,0] op_sel_hi:[0,1]"
             : "=v"(d) : "v"(a), "v"(b)); return d;
}

// C = X * Y, 4x4 row-major stored as v2f[8] (row i: [2i]=cols01, [2i+1]=cols23)
__device__ __forceinline__ void mm4v(v2f* C, const v2f* X, const v2f* Y) {
#pragma unroll
  for (int i = 0; i < 4; ++i) {
    v2f x01 = X[2*i], x23 = X[2*i+1];
#pragma unroll
    for (int jp = 0; jp < 2; ++jp) {
      v2f acc = pk_mul_bl(x01, Y[0 + jp]);
      acc = pk_fma_bh(x01, Y[2 + jp], acc);
      acc = pk_fma_bl(x23, Y[4 + jp], acc);
      acc = pk_fma_bh(x23, Y[6 + jp], acc);
      C[2*i + jp] = acc;
    }
  }
}
// C += X * Y
__device__ __forceinline__ void mm4v_acc(v2f* C, const v2f* X, const v2f* Y) {
#pragma unroll
  for (int i = 0; i < 4; ++i) {
    v2f x01 = X[2*i], x23 = X[2*i+1];
#pragma unroll
    for (int jp = 0; jp < 2; ++jp) {
      v2f acc = C[2*i + jp];
      acc = pk_fma_bl(x01, Y[0 + jp], acc);
      acc = pk_fma_bh(x01, Y[2 + jp], acc);
      acc = pk_fma_bl(x23, Y[4 + jp], acc);
      acc = pk_fma_bh(x23, Y[6 + jp], acc);
      C[2*i + jp] = acc;
    }
  }
}

// Taylor-8 of expm(Q*tau) using shared powers (theta=1.5 scaling done by caller)
__device__ __forceinline__ void taylor8(v2f* T, const v2f* Qm, const v2f* Q2,
                                        const v2f* Q3, const v2f* Q4, float tau) {
  const float t2s = tau * tau, t3s = t2s * tau, t4s = t2s * t2s;
  const v2f tc = mkv2(tau, t2s * 0.5f);                       // (tau, c1)
  const float d0 = t4s * (1.f/24.f);
  const v2f cc = mkv2(t3s * (1.f/6.f), d0);                   // (c2, d0)
  const v2f dA = mkv2(t4s * tau * (1.f/120.f), t4s * t2s * (1.f/720.f));   // (d1,d2)
  const v2f dB = mkv2(t4s * t3s * (1.f/5040.f), t4s * t4s * (1.f/40320.f));// (d3,d4)
  v2f C1[8];
#pragma unroll
  for (int ip = 0; ip < 8; ++ip) {
    v2f a = pk_mul_bl(cc, Q3[ip]);        // c2*Q3
    a = pk_fma_bh(tc, Q2[ip], a);         // + c1*Q2
    T[ip] = pk_fma_bl(tc, Qm[ip], a);     // + tau*Q
    v2f b = pk_mul_bl(dA, Qm[ip]);        // d1*Q
    b = pk_fma_bh(dA, Q2[ip], b);         // + d2*Q2
    b = pk_fma_bl(dB, Q3[ip], b);         // + d3*Q3
    C1[ip] = pk_fma_bh(dB, Q4[ip], b);    // + d4*Q4
  }
  T[0].x += 1.f;  T[2].y += 1.f;  T[5].x += 1.f;  T[7].y += 1.f;
  C1[0].x += d0;  C1[2].y += d0;  C1[5].x += d0;  C1[7].y += d0;
  mm4v_acc(T, Q4, C1);
}

__device__ __forceinline__ void ydy(const v2f* Qm, const v2f* T, const float* f,
                                    float* y, float* dy) {
  const v2f f01 = mkv2(f[0], f[1]), f23 = mkv2(f[2], f[3]);
  const v2f lo = mkv2(1e-30f, 1e-30f);
#pragma unroll
  for (int i = 0; i < 4; ++i) {
    v2f a = pk_mul(v2max(T[2*i], lo), f01);
    a = pk_fma(v2max(T[2*i+1], lo), f23, a);
    y[i] = a.x + a.y;
  }
  const v2f y01 = mkv2(y[0], y[1]), y23 = mkv2(y[2], y[3]);
#pragma unroll
  for (int i = 0; i < 4; ++i) {
    v2f a = pk_mul(Qm[2*i], y01);
    a = pk_fma(Qm[2*i+1], y23, a);
    dy[i] = a.x + a.y;
  }
}

// Both branches with a SHARED wave-uniform squaring count -> the two squaring
// chains interleave (2x ILP on the longest serial section).
__device__ __forceinline__ void site_branch_pair(
    const v2f* Qm, const v2f* Q2, const v2f* Q3, const v2f* Q4,
    float Lmax, float t1, float t2, const float* f1, const float* f2,
    float* y1, float* dy1, float* y2, float* dy2)
{
  float r = Lmax * fmaxf(t1, t2) * 0.66666667f;  // / 1.5
  int m = 0;
  if (r > 1.f) {
    unsigned u = __float_as_uint(r);
    m = (int)(u >> 23) - 127 + (((u & 0x7fffffu) != 0u) ? 1 : 0);
  }
  const float sc = __uint_as_float((unsigned)(127 - m) << 23);

  v2f T1[8], T2[8];
  taylor8(T1, Qm, Q2, Q3, Q4, t1 * sc);
  taylor8(T2, Qm, Q2, Q3, Q4, t2 * sc);

  for (int k = 0; k < m; ++k) {   // m wave-uniform; chains independent -> interleave
    v2f S1[8], S2[8];
    mm4v(S1, T1, T1);
    mm4v(S2, T2, T2);
#pragma unroll
    for (int ip = 0; ip < 8; ++ip) { T1[ip] = S1[ip]; T2[ip] = S2[ip]; }
  }
  ydy(Qm, T1, f1, y1, dy1);
  ydy(Qm, T2, f2, y2, dy2);
}

// column map for the 12 off-diagonal entries of the 4x4 rate matrix
__device__ __forceinline__ int cmapf(int c) { return 5*(c >> 2) + 1 + (c & 3); }

// Prep (grid 32 x 256) — unchanged from R10.
__global__ __launch_bounds__(256) void prep_kernel(
    const float* __restrict__ spg, const float* __restrict__ W1g,
    const float* __restrict__ b1g, const float* __restrict__ Wqg,
    const float* __restrict__ bqg, const float* __restrict__ Wpg,
    const float* __restrict__ bpg,
    _Float16* __restrict__ U0h,
    f16x8* __restrict__ W1Alo, f16x8* __restrict__ W1Ahi,
    f16x8* __restrict__ W1Blo, f16x8* __restrict__ W1Bhi,
    f16x8* __restrict__ WBlo,  f16x8* __restrict__ WBhi,
    float* __restrict__ bias16)
{
  const int jp = blockIdx.x;     // 0..31
  const int s  = threadIdx.x;    // 0..255
  const int j0 = 2*jp, j1 = 2*jp + 1;
  float u0 = b1g[j0], u1 = b1g[j1];
#pragma unroll
  for (int k4 = 0; k4 < 4; ++k4) {
    float4 v4 = reinterpret_cast<const float4*>(spg)[s*4 + k4];
    const float* W0 = W1g + (2 + 4*k4)*64;
    u0 = fmaf(v4.x, W0[j0],       u0);  u1 = fmaf(v4.x, W0[j1],       u1);
    u0 = fmaf(v4.y, W0[64 + j0],  u0);  u1 = fmaf(v4.y, W0[64 + j1],  u1);
    u0 = fmaf(v4.z, W0[128 + j0], u0);  u1 = fmaf(v4.z, W0[128 + j1], u1);
    u0 = fmaf(v4.w, W0[192 + j0], u0);  u1 = fmaf(v4.w, W0[192 + j1], u1);
  }
  U0h[s*64 + j0] = (_Float16)u0;
  U0h[s*64 + j1] = (_Float16)u1;

  if (jp == 0 && s < 64) {
    const int k0 = (s >> 4) * 8;
    f16x8 alo, ahi, blo, bhi;
#pragma unroll
    for (int j = 0; j < 8; ++j) {
      alo[j] = (_Float16)W1g[k0 + j];
      ahi[j] = (_Float16)W1g[32 + k0 + j];
      blo[j] = (_Float16)W1g[64 + k0 + j];
      bhi[j] = (_Float16)W1g[96 + k0 + j];
    }
    W1Alo[s] = alo; W1Ahi[s] = ahi; W1Blo[s] = blo; W1Bhi[s] = bhi;
  }
  if (jp == 1 && s < 64) {
    const int col = s & 15;
    const int k0 = (s >> 4) * 8;
    f16x8 wlo, whi;
#pragma unroll
    for (int j = 0; j < 8; ++j) {
      float vlo, vhi;
      if (col < 12) { vlo = Wqg[(k0 + j)*16 + cmapf(col)];  vhi = Wqg[(32 + k0 + j)*16 + cmapf(col)]; }
      else          { vlo = Wpg[(k0 + j)*4 + (col - 12)];   vhi = Wpg[(32 + k0 + j)*4 + (col - 12)]; }
      wlo[j] = (_Float16)vlo; whi[j] = (_Float16)vhi;
    }
    WBlo[s] = wlo; WBhi[s] = whi;
  }
  if (jp == 2 && s < 16) {
    bias16[s] = (s < 12) ? bqg[cmapf(s)] : bpg[s - 12];
  }
}

// block = one v (1024 blocks), thread = one site s (256 threads).
// Weight fragments reloaded per iteration (live-range control; R4 lesson:
// pinning inflates peak VGPR). cLDS exchange is intra-wave -> no __syncthreads,
// just lgkmcnt(0)+sched_barrier (rule 18).
__global__ __launch_bounds__(256) void mlme_kernel(
    const float* __restrict__ c1g, const float* __restrict__ c2g,
    const float* __restrict__ lf1g, const float* __restrict__ lf2g,
    const _Float16* __restrict__ U0h,
    const f16x8* __restrict__ W1Alo, const f16x8* __restrict__ W1Ahi,
    const f16x8* __restrict__ W1Blo, const f16x8* __restrict__ W1Bhi,
    const f16x8* __restrict__ WBlo,  const f16x8* __restrict__ WBhi,
    const float* __restrict__ bias16g,
    float* __restrict__ outg)
{
  __shared__ float cLDS[256 * 20];  // 20 KB, per-wave 64-row slabs, stride 20
  __shared__ float sred[24];        // 8 per iteration

  const int v = blockIdx.x;
  const int tid = threadIdx.x;
  const int lane = tid & 63;
  const int wid = tid >> 6;
  const int lane16 = lane & 15;
  const int kgrp = lane >> 4;

  // per-thread (redundant, wave-uniform) per-v setup
  const float c10 = c1g[2*v], c11 = c1g[2*v+1];
  const float c20 = c2g[2*v], c21 = c2g[2*v+1];
  float p0, p1, q0, q1;
  {
    float pn = sqrtf(c10*c10 + c11*c11 + EPSf);
    float qn = sqrtf(c20*c20 + c21*c21 + EPSf);
    p0 = c10; p1 = c11; q0 = c20; q1 = c21;
    if (pn > qn) { float rr = qn/pn; p0 = c10*rr; p1 = c11*rr; }
    if (qn > pn) { float rr = pn/qn; q0 = c20*rr; q1 = c21*rr; }
  }
  float alpha = 0.5f, beta = 0.5f;

  // f = exp(log_felsenstein) per thread, once
  float f1[4], f2[4];
  {
    float4 a = reinterpret_cast<const float4*>(lf1g)[v*256 + tid];
    float4 b = reinterpret_cast<const float4*>(lf2g)[v*256 + tid];
    f1[0]=__expf(a.x); f1[1]=__expf(a.y); f1[2]=__expf(a.z); f1[3]=__expf(a.w);
    f2[0]=__expf(b.x); f2[1]=__expf(b.y); f2[2]=__expf(b.z); f2[3]=__expf(b.w);
  }

  const float biasv = bias16g[lane16];   // MFMA C-init (col = lane16 = feature)

  // A-side u base: row = wid*64 + mt*16 + lane16, k-slice = kgrp*8 (+32 for hi)
  const _Float16* Ubase = U0h + (wid*64 + lane16)*64 + kgrp*8;

  for (int it = 0; it < 3; ++it) {
    const float mid0 = p0*alpha + q0*(1.f-alpha);
    const float mid1 = p1*alpha + q1*(1.f-alpha);
    const float par0 = mid0*beta, par1 = mid1*beta;
    const float d10 = c10-par0, d11 = c11-par1;
    const float d20 = c20-par0, d21 = c21-par1;
    const float t1 = sqrtf(d10*d10 + d11*d11 + EPSf);
    const float t2 = sqrtf(d20*d20 + d21*d21 + EPSf);

    // ---- MLP on MFMA: h = relu(u + par0*w1a + par1*w1b) on A-fragments ----
    // fragments loaded here each iteration (L1-hot) to keep expm-phase VGPR low
    const f16x8 w1alo = W1Alo[lane], w1ahi = W1Ahi[lane];
    const f16x8 w1blo = W1Blo[lane], w1bhi = W1Bhi[lane];
    const f16x8 wblo  = WBlo[lane],  wbhi  = WBhi[lane];

    const _Float16 p0h = (_Float16)par0, p1h = (_Float16)par1;
    const f16x8 p0v = {p0h,p0h,p0h,p0h,p0h,p0h,p0h,p0h};
    const f16x8 p1v = {p1h,p1h,p1h,p1h,p1h,p1h,p1h,p1h};
    const f16x8 z8 = {0,0,0,0,0,0,0,0};
    f32x4 accm[4];
#pragma unroll
    for (int mt = 0; mt < 4; ++mt) {
      accm[mt] = (f32x4){biasv, biasv, biasv, biasv};
      f16x8 ulo = *reinterpret_cast<const f16x8*>(Ubase + mt*16*64);
      f16x8 uhi = *reinterpret_cast<const f16x8*>(Ubase + mt*16*64 + 32);
      f16x8 hlo = __builtin_elementwise_max(
          __builtin_elementwise_fma(p1v, w1blo, __builtin_elementwise_fma(p0v, w1alo, ulo)), z8);
      f16x8 hhi = __builtin_elementwise_max(
          __builtin_elementwise_fma(p1v, w1bhi, __builtin_elementwise_fma(p0v, w1ahi, uhi)), z8);
      accm[mt] = __builtin_amdgcn_mfma_f32_16x16x32_f16(hlo, wblo, accm[mt], 0, 0, 0);
      accm[mt] = __builtin_amdgcn_mfma_f32_16x16x32_f16(hhi, wbhi, accm[mt], 0, 0, 0);
    }
    // transpose C within the wave's own slab (intra-wave exchange: no barrier)
#pragma unroll
    for (int mt = 0; mt < 4; ++mt) {
#pragma unroll
      for (int i = 0; i < 4; ++i) {
        cLDS[(wid*64 + mt*16 + kgrp*4 + i)*20 + lane16] = accm[mt][i];
      }
    }
    asm volatile("s_waitcnt lgkmcnt(0)" ::: "memory");
    __builtin_amdgcn_sched_barrier(0);
    float a16[16];
#pragma unroll
    for (int cg = 0; cg < 4; ++cg) {
      f32x4 vv = *reinterpret_cast<const f32x4*>(&cLDS[tid*20 + cg*4]);
#pragma unroll
      for (int i = 0; i < 4; ++i) a16[cg*4 + i] = vv[i];
    }

    // ---- softplus on the 12 off-diagonals; build Q and its 1-norm ----
    float o[12];
#pragma unroll
    for (int k = 0; k < 12; ++k) {
      float xx = a16[k];
      o[k] = fmaxf(xx, 0.f) + __logf(1.f + __expf(-fabsf(xx)));
    }
    const float rs0 = o[0]+o[1]+o[2],  rs1 = o[3]+o[4]+o[5];
    const float rs2 = o[6]+o[7]+o[8],  rs3 = o[9]+o[10]+o[11];
    v2f Qm[8];
    Qm[0] = mkv2(-rs0, o[0]);  Qm[1] = mkv2(o[1], o[2]);
    Qm[2] = mkv2(o[3], -rs1);  Qm[3] = mkv2(o[4], o[5]);
    Qm[4] = mkv2(o[6], o[7]);  Qm[5] = mkv2(-rs2, o[8]);
    Qm[6] = mkv2(o[9], o[10]); Qm[7] = mkv2(o[11], -rs3);
    const float cs0 = rs0 + o[3] + o[6] + o[9];
    const float cs1 = o[0] + rs1 + o[7] + o[10];
    const float cs2 = o[1] + o[4] + rs2 + o[11];
    const float cs3 = o[2] + o[5] + o[8] + rs3;
    const float L1Q = fmaxf(fmaxf(cs0, cs1), fmaxf(cs2, cs3));
    // wave-max of L1Q -> wave-uniform squaring count shared by both branches
    float Lmax = L1Q;
#pragma unroll
    for (int off = 1; off < 64; off <<= 1)
      Lmax = fmaxf(Lmax, __shfl_xor(Lmax, off, 64));

    // unnormalized stationary probs (normalization cancels in gradient ratio)
    float st[4];
    {
      float mx = fmaxf(fmaxf(a16[12], a16[13]), fmaxf(a16[14], a16[15]));
      st[0]=__expf(a16[12]-mx); st[1]=__expf(a16[13]-mx);
      st[2]=__expf(a16[14]-mx); st[3]=__expf(a16[15]-mx);
    }

    // shared powers
    v2f Q2m[8], Q3m[8], Q4m[8];
    mm4v(Q2m, Qm, Qm);
    mm4v(Q3m, Q2m, Qm);
    mm4v(Q4m, Q2m, Q2m);

    float y1[4], dy1[4], y2[4], dy2[4];
    site_branch_pair(Qm, Q2m, Q3m, Q4m, Lmax, t1, t2, f1, f2, y1, dy1, y2, dy2);

    // g_k = sum_a dy_k[a] * (other y)[a] * st[a] / sum_a y1 y2 st
    float den = 0.f, num1 = 0.f, num2 = 0.f;
#pragma unroll
    for (int a = 0; a < 4; ++a) {
      float ys2 = y2[a] * st[a];
      den  = fmaf(y1[a],  ys2, den);
      num1 = fmaf(dy1[a], ys2, num1);
      num2 = fmaf(y1[a] * st[a], dy2[a], num2);
    }
    const float invden = 1.f / den;
    float g1c = num1 * invden;
    float g2c = num2 * invden;

#pragma unroll
    for (int off = 32; off > 0; off >>= 1) {
      g1c += __shfl_xor(g1c, off, 64);
      g2c += __shfl_xor(g2c, off, 64);
    }
    if (lane == 0) { sred[it*8 + wid*2 + 0] = g1c; sred[it*8 + wid*2 + 1] = g2c; }
    __syncthreads();
    // all threads compute the (identical) update redundantly
    {
      float g1 = sred[it*8+0]+sred[it*8+2]+sred[it*8+4]+sred[it*8+6];
      float g2 = sred[it*8+1]+sred[it*8+3]+sred[it*8+5]+sred[it*8+7];
      float db1da = ((par0-c10)*(p0-q0) + (par1-c11)*(p1-q1)) * beta / t1;
      float db2da = ((par0-c20)*(p0-q0) + (par1-c21)*(p1-q1)) * beta / t2;
      float db1db = ((par0-c10)*mid0 + (par1-c11)*mid1) / t1;
      float db2db = ((par0-c20)*mid0 + (par1-c21)*mid1) / t2;
      float ga = g1*db1da + g2*db2da;
      float gb = g1*db1db + g2*db2db;
      ga = fminf(1.f, fmaxf(-1.f, ga));
      gb = fminf(1.f, fmaxf(-1.f, gb));
      alpha = fminf(1.f, fmaxf(0.f, alpha + 0.1f*ga));
      beta  = fminf(1.f, fmaxf(0.f, beta  + 0.1f*gb));
    }
  }

  if (tid == 0) {
    float m0 = p0*alpha + q0*(1.f-alpha);
    float m1 = p1*alpha + q1*(1.f-alpha);
    outg[2*v]   = m0*beta;
    outg[2*v+1] = m1*beta;
  }
}

extern "C" void kernel_launch(void* const* d_in, const int* in_sizes, int n_in,
                              void* d_out, int out_size, void* d_ws, size_t ws_size,
                              hipStream_t stream) {
  (void)in_sizes; (void)n_in; (void)ws_size; (void)out_size;
  const float* c1  = (const float*)d_in[0];
  const float* c2  = (const float*)d_in[1];
  const float* lf1 = (const float*)d_in[2];
  const float* lf2 = (const float*)d_in[3];
  const float* sp  = (const float*)d_in[4];
  const float* W1  = (const float*)d_in[5];
  const float* b1  = (const float*)d_in[6];
  const float* Wq  = (const float*)d_in[7];
  const float* bq  = (const float*)d_in[8];
  const float* Wp  = (const float*)d_in[9];
  const float* bp  = (const float*)d_in[10];
  float* out = (float*)d_out;

  char* ws = (char*)d_ws;
  _Float16* U0h   = (_Float16*)ws;                 // 256*64*2 = 32768 B
  f16x8* W1Alo = (f16x8*)(ws + 32768);             // 64*16 = 1024 B
  f16x8* W1Ahi = (f16x8*)(ws + 33792);
  f16x8* W1Blo = (f16x8*)(ws + 34816);
  f16x8* W1Bhi = (f16x8*)(ws + 35840);
  f16x8* WBlo  = (f16x8*)(ws + 36864);
  f16x8* WBhi  = (f16x8*)(ws + 37888);
  float* bias16 = (float*)(ws + 38912);            // 64 B

  prep_kernel<<<dim3(32), dim3(256), 0, stream>>>(sp, W1, b1, Wq, bq, Wp, bp,
                                                  U0h, W1Alo, W1Ahi, W1Blo, W1Bhi,
                                                  WBlo, WBhi, bias16);
  mlme_kernel<<<dim3(1024), dim3(256), 0, stream>>>(
      c1, c2, lf1, lf2, U0h, W1Alo, W1Ahi, W1Blo, W1Bhi, WBlo, WBhi, bias16, out);
}

// Round 12
// 43.404 us; speedup vs baseline: 1.0419x; 1.0419x over previous
//
#include <hip/hip_runtime.h>
#include <math.h>

#define EPSf 1e-12f

typedef float v2f __attribute__((ext_vector_type(2)));
typedef float f32x4 __attribute__((ext_vector_type(4)));
typedef _Float16 f16x8 __attribute__((ext_vector_type(8)));

__device__ __forceinline__ v2f mkv2(float a, float b) { v2f r; r.x = a; r.y = b; return r; }

// ---- forced VOP3P packed-f32 ops ----
// NOTE: gfx950 has NO v_pk_max_f32 / v_pk_min_f32 — only fma/mul/add/mov (R9 lesson).
__device__ __forceinline__ v2f pk_fma(v2f a, v2f b, v2f c) {
  v2f d; asm("v_pk_fma_f32 %0, %1, %2, %3" : "=v"(d) : "v"(a), "v"(b), "v"(c)); return d;
}
__device__ __forceinline__ v2f pk_mul(v2f a, v2f b) {
  v2f d; asm("v_pk_mul_f32 %0, %1, %2" : "=v"(d) : "v"(a), "v"(b)); return d;
}
__device__ __forceinline__ v2f v2max(v2f a, v2f b) { return __builtin_elementwise_max(a, b); }
// broadcast-lo / broadcast-hi of S0 via op_sel (free scalar*vector)
__device__ __forceinline__ v2f pk_fma_bl(v2f a, v2f b, v2f c) {
  v2f d; asm("v_pk_fma_f32 %0, %1, %2, %3 op_sel:[0,0,0] op_sel_hi:[0,1,1]"
             : "=v"(d) : "v"(a), "v"(b), "v"(c)); return d;
}
__device__ __forceinline__ v2f pk_fma_bh(v2f a, v2f b, v2f c) {
  v2f d; asm("v_pk_fma_f32 %0, %1, %2, %3 op_sel:[1,0,0] op_sel_hi:[1,1,1]"
             : "=v"(d) : "v"(a), "v"(b), "v"(c)); return d;
}
__device__ __forceinline__ v2f pk_mul_bl(v2f a, v2f b) {
  v2f d; asm("v_pk_mul_f32 %0, %1, %2 op_sel:[0,0] op_sel_hi:[0,1]"
             : "=v"(d) : "v"(a), "v"(b)); return d;
}

// C = X * Y, 4x4 row-major stored as v2f[8] (row i: [2i]=cols01, [2i+1]=cols23)
__device__ __forceinline__ void mm4v(v2f* C, const v2f* X, const v2f* Y) {
#pragma unroll
  for (int i = 0; i < 4; ++i) {
    v2f x01 = X[2*i], x23 = X[2*i+1];
#pragma unroll
    for (int jp = 0; jp < 2; ++jp) {
      v2f acc = pk_mul_bl(x01, Y[0 + jp]);
      acc = pk_fma_bh(x01, Y[2 + jp], acc);
      acc = pk_fma_bl(x23, Y[4 + jp], acc);
      acc = pk_fma_bh(x23, Y[6 + jp], acc);
      C[2*i + jp] = acc;
    }
  }
}
// C += X * Y
__device__ __forceinline__ void mm4v_acc(v2f* C, const v2f* X, const v2f* Y) {
#pragma unroll
  for (int i = 0; i < 4; ++i) {
    v2f x01 = X[2*i], x23 = X[2*i+1];
#pragma unroll
    for (int jp = 0; jp < 2; ++jp) {
      v2f acc = C[2*i + jp];
      acc = pk_fma_bl(x01, Y[0 + jp], acc);
      acc = pk_fma_bh(x01, Y[2 + jp], acc);
      acc = pk_fma_bl(x23, Y[4 + jp], acc);
      acc = pk_fma_bh(x23, Y[6 + jp], acc);
      C[2*i + jp] = acc;
    }
  }
}

// expm(Q t) @ f via scaled Taylor-8 (theta=1.5) + repeated squaring.
// Lmax wave-uniform -> m wave-uniform (no divergent squaring passes).
// y = clip(P,1e-30) @ f ; dy = Q @ y  (exact: dP/dt = Q P)
__device__ __forceinline__ void site_branch(const v2f* Qm, const v2f* Q2, const v2f* Q3,
                                            const v2f* Q4, float Lmax, float t,
                                            const float* f, float* y, float* dy) {
  float r = Lmax * t * 0.66666667f;  // / 1.5
  int m = 0;
  if (r > 1.f) {
    unsigned u = __float_as_uint(r);
    m = (int)(u >> 23) - 127 + (((u & 0x7fffffu) != 0u) ? 1 : 0);
  }
  const float tau = t * __uint_as_float((unsigned)(127 - m) << 23);
  const float t2s = tau * tau, t3s = t2s * tau, t4s = t2s * t2s;
  // packed coefficient pairs for op_sel broadcasts
  const v2f tc = mkv2(tau, t2s * 0.5f);                       // (tau, c1)
  const float d0 = t4s * (1.f/24.f);
  const v2f cc = mkv2(t3s * (1.f/6.f), d0);                   // (c2, d0)
  const v2f dA = mkv2(t4s * tau * (1.f/120.f), t4s * t2s * (1.f/720.f));   // (d1,d2)
  const v2f dB = mkv2(t4s * t3s * (1.f/5040.f), t4s * t4s * (1.f/40320.f));// (d3,d4)

  // T = I + tau*Q + c1*Q2 + c2*Q3 ; C1 = d0*I + d1*Q + d2*Q2 + d3*Q3 + d4*Q4
  v2f T[8], C1[8];
#pragma unroll
  for (int ip = 0; ip < 8; ++ip) {
    v2f a = pk_mul_bl(cc, Q3[ip]);        // c2*Q3
    a = pk_fma_bh(tc, Q2[ip], a);         // + c1*Q2
    T[ip] = pk_fma_bl(tc, Qm[ip], a);     // + tau*Q
    v2f b = pk_mul_bl(dA, Qm[ip]);        // d1*Q
    b = pk_fma_bh(dA, Q2[ip], b);         // + d2*Q2
    b = pk_fma_bl(dB, Q3[ip], b);         // + d3*Q3
    C1[ip] = pk_fma_bh(dB, Q4[ip], b);    // + d4*Q4
  }
  T[0].x += 1.f;  T[2].y += 1.f;  T[5].x += 1.f;  T[7].y += 1.f;
  C1[0].x += d0;  C1[2].y += d0;  C1[5].x += d0;  C1[7].y += d0;
  mm4v_acc(T, Q4, C1);           // T = Taylor-8 of expm(Q*tau)

  for (int k = 0; k < m; ++k) {  // m wave-uniform: no exec-mask divergence
    v2f S[8];
    mm4v(S, T, T);
#pragma unroll
    for (int ip = 0; ip < 8; ++ip) T[ip] = S[ip];
  }

  const v2f f01 = mkv2(f[0], f[1]), f23 = mkv2(f[2], f[3]);
  const v2f lo = mkv2(1e-30f, 1e-30f);
#pragma unroll
  for (int i = 0; i < 4; ++i) {
    v2f a = pk_mul(v2max(T[2*i], lo), f01);
    a = pk_fma(v2max(T[2*i+1], lo), f23, a);
    y[i] = a.x + a.y;
  }
  const v2f y01 = mkv2(y[0], y[1]), y23 = mkv2(y[2], y[3]);
#pragma unroll
  for (int i = 0; i < 4; ++i) {
    v2f a = pk_mul(Qm[2*i], y01);
    a = pk_fma(Qm[2*i+1], y23, a);
    dy[i] = a.x + a.y;
  }
}

// column map for the 12 off-diagonal entries of the 4x4 rate matrix
__device__ __forceinline__ int cmapf(int c) { return 5*(c >> 2) + 1 + (c & 3); }

// Prep (grid 32 x 256) — unchanged.
__global__ __launch_bounds__(256) void prep_kernel(
    const float* __restrict__ spg, const float* __restrict__ W1g,
    const float* __restrict__ b1g, const float* __restrict__ Wqg,
    const float* __restrict__ bqg, const float* __restrict__ Wpg,
    const float* __restrict__ bpg,
    _Float16* __restrict__ U0h,
    f16x8* __restrict__ W1Alo, f16x8* __restrict__ W1Ahi,
    f16x8* __restrict__ W1Blo, f16x8* __restrict__ W1Bhi,
    f16x8* __restrict__ WBlo,  f16x8* __restrict__ WBhi,
    float* __restrict__ bias16)
{
  const int jp = blockIdx.x;     // 0..31
  const int s  = threadIdx.x;    // 0..255
  const int j0 = 2*jp, j1 = 2*jp + 1;
  float u0 = b1g[j0], u1 = b1g[j1];
#pragma unroll
  for (int k4 = 0; k4 < 4; ++k4) {
    float4 v4 = reinterpret_cast<const float4*>(spg)[s*4 + k4];
    const float* W0 = W1g + (2 + 4*k4)*64;
    u0 = fmaf(v4.x, W0[j0],       u0);  u1 = fmaf(v4.x, W0[j1],       u1);
    u0 = fmaf(v4.y, W0[64 + j0],  u0);  u1 = fmaf(v4.y, W0[64 + j1],  u1);
    u0 = fmaf(v4.z, W0[128 + j0], u0);  u1 = fmaf(v4.z, W0[128 + j1], u1);
    u0 = fmaf(v4.w, W0[192 + j0], u0);  u1 = fmaf(v4.w, W0[192 + j1], u1);
  }
  U0h[s*64 + j0] = (_Float16)u0;
  U0h[s*64 + j1] = (_Float16)u1;

  if (jp == 0 && s < 64) {
    const int k0 = (s >> 4) * 8;
    f16x8 alo, ahi, blo, bhi;
#pragma unroll
    for (int j = 0; j < 8; ++j) {
      alo[j] = (_Float16)W1g[k0 + j];
      ahi[j] = (_Float16)W1g[32 + k0 + j];
      blo[j] = (_Float16)W1g[64 + k0 + j];
      bhi[j] = (_Float16)W1g[96 + k0 + j];
    }
    W1Alo[s] = alo; W1Ahi[s] = ahi; W1Blo[s] = blo; W1Bhi[s] = bhi;
  }
  if (jp == 1 && s < 64) {
    const int col = s & 15;
    const int k0 = (s >> 4) * 8;
    f16x8 wlo, whi;
#pragma unroll
    for (int j = 0; j < 8; ++j) {
      float vlo, vhi;
      if (col < 12) { vlo = Wqg[(k0 + j)*16 + cmapf(col)];  vhi = Wqg[(32 + k0 + j)*16 + cmapf(col)]; }
      else          { vlo = Wpg[(k0 + j)*4 + (col - 12)];   vhi = Wpg[(32 + k0 + j)*4 + (col - 12)]; }
      wlo[j] = (_Float16)vlo; whi[j] = (_Float16)vhi;
    }
    WBlo[s] = wlo; WBhi[s] = whi;
  }
  if (jp == 2 && s < 16) {
    bias16[s] = (s < 12) ? bqg[cmapf(s)] : bpg[s - 12];
  }
}

// block = one v (1024 blocks), thread = one site s (256 threads).
// R10 structure (pinned fragments, separate branches) + bias-in-C-init +
// intra-wave cLDS fence instead of block barrier. Occupancy is grid-capped at
// 4 waves/SIMD, so every VGPR matters: no cross-branch fusion (R11 lesson).
__global__ __launch_bounds__(256) void mlme_kernel(
    const float* __restrict__ c1g, const float* __restrict__ c2g,
    const float* __restrict__ lf1g, const float* __restrict__ lf2g,
    const _Float16* __restrict__ U0h,
    const f16x8* __restrict__ W1Alo, const f16x8* __restrict__ W1Ahi,
    const f16x8* __restrict__ W1Blo, const f16x8* __restrict__ W1Bhi,
    const f16x8* __restrict__ WBlo,  const f16x8* __restrict__ WBhi,
    const float* __restrict__ bias16g,
    float* __restrict__ outg)
{
  __shared__ float cLDS[256 * 20];  // 20 KB, per-wave 64-row slabs, stride 20
  __shared__ float sred[24];        // 8 per iteration

  const int v = blockIdx.x;
  const int tid = threadIdx.x;
  const int lane = tid & 63;
  const int wid = tid >> 6;
  const int lane16 = lane & 15;
  const int kgrp = lane >> 4;

  // pinned per-lane fragments (L2-hot, loaded once — R10 proved this tier works)
  const f16x8 w1alo = W1Alo[lane], w1ahi = W1Ahi[lane];
  const f16x8 w1blo = W1Blo[lane], w1bhi = W1Bhi[lane];
  const f16x8 wblo  = WBlo[lane],  wbhi  = WBhi[lane];

  // per-thread (redundant, wave-uniform) per-v setup
  const float c10 = c1g[2*v], c11 = c1g[2*v+1];
  const float c20 = c2g[2*v], c21 = c2g[2*v+1];
  float p0, p1, q0, q1;
  {
    float pn = sqrtf(c10*c10 + c11*c11 + EPSf);
    float qn = sqrtf(c20*c20 + c21*c21 + EPSf);
    p0 = c10; p1 = c11; q0 = c20; q1 = c21;
    if (pn > qn) { float rr = qn/pn; p0 = c10*rr; p1 = c11*rr; }
    if (qn > pn) { float rr = pn/qn; q0 = c20*rr; q1 = c21*rr; }
  }
  float alpha = 0.5f, beta = 0.5f;

  // f = exp(log_felsenstein) per thread, once
  float f1[4], f2[4];
  {
    float4 a = reinterpret_cast<const float4*>(lf1g)[v*256 + tid];
    float4 b = reinterpret_cast<const float4*>(lf2g)[v*256 + tid];
    f1[0]=__expf(a.x); f1[1]=__expf(a.y); f1[2]=__expf(a.z); f1[3]=__expf(a.w);
    f2[0]=__expf(b.x); f2[1]=__expf(b.y); f2[2]=__expf(b.z); f2[3]=__expf(b.w);
  }

  const float biasv = bias16g[lane16];   // MFMA C-init (C col = lane16 = feature)

  // A-side u base: row = wid*64 + mt*16 + lane16, k-slice = kgrp*8 (+32 for hi)
  const _Float16* Ubase = U0h + (wid*64 + lane16)*64 + kgrp*8;

  for (int it = 0; it < 3; ++it) {
    const float mid0 = p0*alpha + q0*(1.f-alpha);
    const float mid1 = p1*alpha + q1*(1.f-alpha);
    const float par0 = mid0*beta, par1 = mid1*beta;
    const float d10 = c10-par0, d11 = c11-par1;
    const float d20 = c20-par0, d21 = c21-par1;
    const float t1 = sqrtf(d10*d10 + d11*d11 + EPSf);
    const float t2 = sqrtf(d20*d20 + d21*d21 + EPSf);

    // ---- MLP on MFMA: h = relu(u + par0*w1a + par1*w1b) on A-fragments ----
    const _Float16 p0h = (_Float16)par0, p1h = (_Float16)par1;
    const f16x8 p0v = {p0h,p0h,p0h,p0h,p0h,p0h,p0h,p0h};
    const f16x8 p1v = {p1h,p1h,p1h,p1h,p1h,p1h,p1h,p1h};
    const f16x8 z8 = {0,0,0,0,0,0,0,0};
    f32x4 accm[4];
#pragma unroll
    for (int mt = 0; mt < 4; ++mt) {
      accm[mt] = (f32x4){biasv, biasv, biasv, biasv};
      f16x8 ulo = *reinterpret_cast<const f16x8*>(Ubase + mt*16*64);
      f16x8 uhi = *reinterpret_cast<const f16x8*>(Ubase + mt*16*64 + 32);
      f16x8 hlo = __builtin_elementwise_max(
          __builtin_elementwise_fma(p1v, w1blo, __builtin_elementwise_fma(p0v, w1alo, ulo)), z8);
      f16x8 hhi = __builtin_elementwise_max(
          __builtin_elementwise_fma(p1v, w1bhi, __builtin_elementwise_fma(p0v, w1ahi, uhi)), z8);
      accm[mt] = __builtin_amdgcn_mfma_f32_16x16x32_f16(hlo, wblo, accm[mt], 0, 0, 0);
      accm[mt] = __builtin_amdgcn_mfma_f32_16x16x32_f16(hhi, wbhi, accm[mt], 0, 0, 0);
    }
    // transpose C within the wave's own 64-row slab (intra-wave: no block barrier)
#pragma unroll
    for (int mt = 0; mt < 4; ++mt) {
#pragma unroll
      for (int i = 0; i < 4; ++i) {
        cLDS[(wid*64 + mt*16 + kgrp*4 + i)*20 + lane16] = accm[mt][i];
      }
    }
    asm volatile("s_waitcnt lgkmcnt(0)" ::: "memory");
    __builtin_amdgcn_sched_barrier(0);
    float a16[16];
#pragma unroll
    for (int cg = 0; cg < 4; ++cg) {
      f32x4 vv = *reinterpret_cast<const f32x4*>(&cLDS[tid*20 + cg*4]);
#pragma unroll
      for (int i = 0; i < 4; ++i) a16[cg*4 + i] = vv[i];
    }

    // ---- softplus on the 12 off-diagonals; build Q and its 1-norm ----
    float o[12];
#pragma unroll
    for (int k = 0; k < 12; ++k) {
      float xx = a16[k];
      o[k] = fmaxf(xx, 0.f) + __logf(1.f + __expf(-fabsf(xx)));
    }
    const float rs0 = o[0]+o[1]+o[2],  rs1 = o[3]+o[4]+o[5];
    const float rs2 = o[6]+o[7]+o[8],  rs3 = o[9]+o[10]+o[11];
    v2f Qm[8];
    Qm[0] = mkv2(-rs0, o[0]);  Qm[1] = mkv2(o[1], o[2]);
    Qm[2] = mkv2(o[3], -rs1);  Qm[3] = mkv2(o[4], o[5]);
    Qm[4] = mkv2(o[6], o[7]);  Qm[5] = mkv2(-rs2, o[8]);
    Qm[6] = mkv2(o[9], o[10]); Qm[7] = mkv2(o[11], -rs3);
    const float cs0 = rs0 + o[3] + o[6] + o[9];
    const float cs1 = o[0] + rs1 + o[7] + o[10];
    const float cs2 = o[1] + o[4] + rs2 + o[11];
    const float cs3 = o[2] + o[5] + o[8] + rs3;
    const float L1Q = fmaxf(fmaxf(cs0, cs1), fmaxf(cs2, cs3));
    // wave-max of L1Q -> wave-uniform squaring count for both branches
    float Lmax = L1Q;
#pragma unroll
    for (int off = 1; off < 64; off <<= 1)
      Lmax = fmaxf(Lmax, __shfl_xor(Lmax, off, 64));

    // unnormalized stationary probs (normalization cancels in gradient ratio)
    float st[4];
    {
      float mx = fmaxf(fmaxf(a16[12], a16[13]), fmaxf(a16[14], a16[15]));
      st[0]=__expf(a16[12]-mx); st[1]=__expf(a16[13]-mx);
      st[2]=__expf(a16[14]-mx); st[3]=__expf(a16[15]-mx);
    }

    // shared powers
    v2f Q2m[8], Q3m[8], Q4m[8];
    mm4v(Q2m, Qm, Qm);
    mm4v(Q3m, Q2m, Qm);
    mm4v(Q4m, Q2m, Q2m);

    float y1[4], dy1[4], y2[4], dy2[4];
    site_branch(Qm, Q2m, Q3m, Q4m, Lmax, t1, f1, y1, dy1);
    site_branch(Qm, Q2m, Q3m, Q4m, Lmax, t2, f2, y2, dy2);

    // g_k = sum_a dy_k[a] * (other y)[a] * st[a] / sum_a y1 y2 st
    float den = 0.f, num1 = 0.f, num2 = 0.f;
#pragma unroll
    for (int a = 0; a < 4; ++a) {
      float ys2 = y2[a] * st[a];
      den  = fmaf(y1[a],  ys2, den);
      num1 = fmaf(dy1[a], ys2, num1);
      num2 = fmaf(y1[a] * st[a], dy2[a], num2);
    }
    const float invden = 1.f / den;
    float g1c = num1 * invden;
    float g2c = num2 * invden;

#pragma unroll
    for (int off = 32; off > 0; off >>= 1) {
      g1c += __shfl_xor(g1c, off, 64);
      g2c += __shfl_xor(g2c, off, 64);
    }
    if (lane == 0) { sred[it*8 + wid*2 + 0] = g1c; sred[it*8 + wid*2 + 1] = g2c; }
    __syncthreads();
    // all threads compute the (identical) update redundantly
    {
      float g1 = sred[it*8+0]+sred[it*8+2]+sred[it*8+4]+sred[it*8+6];
      float g2 = sred[it*8+1]+sred[it*8+3]+sred[it*8+5]+sred[it*8+7];
      float db1da = ((par0-c10)*(p0-q0) + (par1-c11)*(p1-q1)) * beta / t1;
      float db2da = ((par0-c20)*(p0-q0) + (par1-c21)*(p1-q1)) * beta / t2;
      float db1db = ((par0-c10)*mid0 + (par1-c11)*mid1) / t1;
      float db2db = ((par0-c20)*mid0 + (par1-c21)*mid1) / t2;
      float ga = g1*db1da + g2*db2da;
      float gb = g1*db1db + g2*db2db;
      ga = fminf(1.f, fmaxf(-1.f, ga));
      gb = fminf(1.f, fmaxf(-1.f, gb));
      alpha = fminf(1.f, fmaxf(0.f, alpha + 0.1f*ga));
      beta  = fminf(1.f, fmaxf(0.f, beta  + 0.1f*gb));
    }
  }

  if (tid == 0) {
    float m0 = p0*alpha + q0*(1.f-alpha);
    float m1 = p1*alpha + q1*(1.f-alpha);
    outg[2*v]   = m0*beta;
    outg[2*v+1] = m1*beta;
  }
}

extern "C" void kernel_launch(void* const* d_in, const int* in_sizes, int n_in,
                              void* d_out, int out_size, void* d_ws, size_t ws_size,
                              hipStream_t stream) {
  (void)in_sizes; (void)n_in; (void)ws_size; (void)out_size;
  const float* c1  = (const float*)d_in[0];
  const float* c2  = (const float*)d_in[1];
  const float* lf1 = (const float*)d_in[2];
  const float* lf2 = (const float*)d_in[3];
  const float* sp  = (const float*)d_in[4];
  const float* W1  = (const float*)d_in[5];
  const float* b1  = (const float*)d_in[6];
  const float* Wq  = (const float*)d_in[7];
  const float* bq  = (const float*)d_in[8];
  const float* Wp  = (const float*)d_in[9];
  const float* bp  = (const float*)d_in[10];
  float* out = (float*)d_out;

  char* ws = (char*)d_ws;
  _Float16* U0h   = (_Float16*)ws;                 // 256*64*2 = 32768 B
  f16x8* W1Alo = (f16x8*)(ws + 32768);             // 64*16 = 1024 B
  f16x8* W1Ahi = (f16x8*)(ws + 33792);
  f16x8* W1Blo = (f16x8*)(ws + 34816);
  f16x8* W1Bhi = (f16x8*)(ws + 35840);
  f16x8* WBlo  = (f16x8*)(ws + 36864);
  f16x8* WBhi  = (f16x8*)(ws + 37888);
  float* bias16 = (float*)(ws + 38912);            // 64 B

  prep_kernel<<<dim3(32), dim3(256), 0, stream>>>(sp, W1, b1, Wq, bq, Wp, bp,
                                                  U0h, W1Alo, W1Ahi, W1Blo, W1Bhi,
                                                  WBlo, WBhi, bias16);
  mlme_kernel<<<dim3(1024), dim3(256), 0, stream>>>(
      c1, c2, lf1, lf2, U0h, W1Alo, W1Ahi, W1Blo, W1Bhi, WBlo, WBhi, bias16, out);
}

// Round 13
// 42.240 us; speedup vs baseline: 1.0706x; 1.0276x over previous
//
#include <hip/hip_runtime.h>
#include <math.h>

#define EPSf 1e-12f

typedef float v2f __attribute__((ext_vector_type(2)));
typedef float f32x4 __attribute__((ext_vector_type(4)));
typedef _Float16 f16x8 __attribute__((ext_vector_type(8)));

__device__ __forceinline__ v2f mkv2(float a, float b) { v2f r; r.x = a; r.y = b; return r; }

// fast 1-ulp-class approximations (tolerance headroom 14x; feeds expm/grad only)
__device__ __forceinline__ float frcp(float x) { return __builtin_amdgcn_rcpf(x); }
__device__ __forceinline__ float fsqrt_fast(float x) {
  return x * __builtin_amdgcn_rsqf(x);   // x>0 always (eps-padded)
}

// ---- forced VOP3P packed-f32 ops ----
// NOTE: gfx950 has NO v_pk_max_f32 / v_pk_min_f32 — only fma/mul/add/mov (R9 lesson).
__device__ __forceinline__ v2f pk_fma(v2f a, v2f b, v2f c) {
  v2f d; asm("v_pk_fma_f32 %0, %1, %2, %3" : "=v"(d) : "v"(a), "v"(b), "v"(c)); return d;
}
__device__ __forceinline__ v2f pk_mul(v2f a, v2f b) {
  v2f d; asm("v_pk_mul_f32 %0, %1, %2" : "=v"(d) : "v"(a), "v"(b)); return d;
}
__device__ __forceinline__ v2f v2max(v2f a, v2f b) { return __builtin_elementwise_max(a, b); }
// broadcast-lo / broadcast-hi of S0 via op_sel (free scalar*vector)
__device__ __forceinline__ v2f pk_fma_bl(v2f a, v2f b, v2f c) {
  v2f d; asm("v_pk_fma_f32 %0, %1, %2, %3 op_sel:[0,0,0] op_sel_hi:[0,1,1]"
             : "=v"(d) : "v"(a), "v"(b), "v"(c)); return d;
}
__device__ __forceinline__ v2f pk_fma_bh(v2f a, v2f b, v2f c) {
  v2f d; asm("v_pk_fma_f32 %0, %1, %2, %3 op_sel:[1,0,0] op_sel_hi:[1,1,1]"
             : "=v"(d) : "v"(a), "v"(b), "v"(c)); return d;
}
__device__ __forceinline__ v2f pk_mul_bl(v2f a, v2f b) {
  v2f d; asm("v_pk_mul_f32 %0, %1, %2 op_sel:[0,0] op_sel_hi:[0,1]"
             : "=v"(d) : "v"(a), "v"(b)); return d;
}

// C = X * Y, 4x4 row-major stored as v2f[8] (row i: [2i]=cols01, [2i+1]=cols23)
__device__ __forceinline__ void mm4v(v2f* C, const v2f* X, const v2f* Y) {
#pragma unroll
  for (int i = 0; i < 4; ++i) {
    v2f x01 = X[2*i], x23 = X[2*i+1];
#pragma unroll
    for (int jp = 0; jp < 2; ++jp) {
      v2f acc = pk_mul_bl(x01, Y[0 + jp]);
      acc = pk_fma_bh(x01, Y[2 + jp], acc);
      acc = pk_fma_bl(x23, Y[4 + jp], acc);
      acc = pk_fma_bh(x23, Y[6 + jp], acc);
      C[2*i + jp] = acc;
    }
  }
}
// C += X * Y
__device__ __forceinline__ void mm4v_acc(v2f* C, const v2f* X, const v2f* Y) {
#pragma unroll
  for (int i = 0; i < 4; ++i) {
    v2f x01 = X[2*i], x23 = X[2*i+1];
#pragma unroll
    for (int jp = 0; jp < 2; ++jp) {
      v2f acc = C[2*i + jp];
      acc = pk_fma_bl(x01, Y[0 + jp], acc);
      acc = pk_fma_bh(x01, Y[2 + jp], acc);
      acc = pk_fma_bl(x23, Y[4 + jp], acc);
      acc = pk_fma_bh(x23, Y[6 + jp], acc);
      C[2*i + jp] = acc;
    }
  }
}

// expm(Q t) @ f via scaled Taylor-8 (theta=1.5) + repeated squaring.
// Lmax wave-uniform -> m wave-uniform (no divergent squaring passes).
// y = clip(P,1e-30) @ f ; dy = Q @ y  (exact: dP/dt = Q P)
__device__ __forceinline__ void site_branch(const v2f* Qm, const v2f* Q2, const v2f* Q3,
                                            const v2f* Q4, float Lmax, float t,
                                            const float* f, float* y, float* dy) {
  float r = Lmax * t * 0.66666667f;  // / 1.5
  int m = 0;
  if (r > 1.f) {
    unsigned u = __float_as_uint(r);
    m = (int)(u >> 23) - 127 + (((u & 0x7fffffu) != 0u) ? 1 : 0);
  }
  const float tau = t * __uint_as_float((unsigned)(127 - m) << 23);
  const float t2s = tau * tau, t3s = t2s * tau, t4s = t2s * t2s;
  // packed coefficient pairs for op_sel broadcasts
  const v2f tc = mkv2(tau, t2s * 0.5f);                       // (tau, c1)
  const float d0 = t4s * (1.f/24.f);
  const v2f cc = mkv2(t3s * (1.f/6.f), d0);                   // (c2, d0)
  const v2f dA = mkv2(t4s * tau * (1.f/120.f), t4s * t2s * (1.f/720.f));   // (d1,d2)
  const v2f dB = mkv2(t4s * t3s * (1.f/5040.f), t4s * t4s * (1.f/40320.f));// (d3,d4)

  // T = I + tau*Q + c1*Q2 + c2*Q3 ; C1 = d0*I + d1*Q + d2*Q2 + d3*Q3 + d4*Q4
  v2f T[8], C1[8];
#pragma unroll
  for (int ip = 0; ip < 8; ++ip) {
    v2f a = pk_mul_bl(cc, Q3[ip]);        // c2*Q3
    a = pk_fma_bh(tc, Q2[ip], a);         // + c1*Q2
    T[ip] = pk_fma_bl(tc, Qm[ip], a);     // + tau*Q
    v2f b = pk_mul_bl(dA, Qm[ip]);        // d1*Q
    b = pk_fma_bh(dA, Q2[ip], b);         // + d2*Q2
    b = pk_fma_bl(dB, Q3[ip], b);         // + d3*Q3
    C1[ip] = pk_fma_bh(dB, Q4[ip], b);    // + d4*Q4
  }
  T[0].x += 1.f;  T[2].y += 1.f;  T[5].x += 1.f;  T[7].y += 1.f;
  C1[0].x += d0;  C1[2].y += d0;  C1[5].x += d0;  C1[7].y += d0;
  mm4v_acc(T, Q4, C1);           // T = Taylor-8 of expm(Q*tau)

  for (int k = 0; k < m; ++k) {  // m wave-uniform: no exec-mask divergence
    v2f S[8];
    mm4v(S, T, T);
#pragma unroll
    for (int ip = 0; ip < 8; ++ip) T[ip] = S[ip];
  }

  const v2f f01 = mkv2(f[0], f[1]), f23 = mkv2(f[2], f[3]);
  const v2f lo = mkv2(1e-30f, 1e-30f);
#pragma unroll
  for (int i = 0; i < 4; ++i) {
    v2f a = pk_mul(v2max(T[2*i], lo), f01);
    a = pk_fma(v2max(T[2*i+1], lo), f23, a);
    y[i] = a.x + a.y;
  }
  const v2f y01 = mkv2(y[0], y[1]), y23 = mkv2(y[2], y[3]);
#pragma unroll
  for (int i = 0; i < 4; ++i) {
    v2f a = pk_mul(Qm[2*i], y01);
    a = pk_fma(Qm[2*i+1], y23, a);
    dy[i] = a.x + a.y;
  }
}

// column map for the 12 off-diagonal entries of the 4x4 rate matrix
__device__ __forceinline__ int cmapf(int c) { return 5*(c >> 2) + 1 + (c & 3); }

// Prep (grid 32 x 256) — unchanged.
__global__ __launch_bounds__(256) void prep_kernel(
    const float* __restrict__ spg, const float* __restrict__ W1g,
    const float* __restrict__ b1g, const float* __restrict__ Wqg,
    const float* __restrict__ bqg, const float* __restrict__ Wpg,
    const float* __restrict__ bpg,
    _Float16* __restrict__ U0h,
    f16x8* __restrict__ W1Alo, f16x8* __restrict__ W1Ahi,
    f16x8* __restrict__ W1Blo, f16x8* __restrict__ W1Bhi,
    f16x8* __restrict__ WBlo,  f16x8* __restrict__ WBhi,
    float* __restrict__ bias16)
{
  const int jp = blockIdx.x;     // 0..31
  const int s  = threadIdx.x;    // 0..255
  const int j0 = 2*jp, j1 = 2*jp + 1;
  float u0 = b1g[j0], u1 = b1g[j1];
#pragma unroll
  for (int k4 = 0; k4 < 4; ++k4) {
    float4 v4 = reinterpret_cast<const float4*>(spg)[s*4 + k4];
    const float* W0 = W1g + (2 + 4*k4)*64;
    u0 = fmaf(v4.x, W0[j0],       u0);  u1 = fmaf(v4.x, W0[j1],       u1);
    u0 = fmaf(v4.y, W0[64 + j0],  u0);  u1 = fmaf(v4.y, W0[64 + j1],  u1);
    u0 = fmaf(v4.z, W0[128 + j0], u0);  u1 = fmaf(v4.z, W0[128 + j1], u1);
    u0 = fmaf(v4.w, W0[192 + j0], u0);  u1 = fmaf(v4.w, W0[192 + j1], u1);
  }
  U0h[s*64 + j0] = (_Float16)u0;
  U0h[s*64 + j1] = (_Float16)u1;

  if (jp == 0 && s < 64) {
    const int k0 = (s >> 4) * 8;
    f16x8 alo, ahi, blo, bhi;
#pragma unroll
    for (int j = 0; j < 8; ++j) {
      alo[j] = (_Float16)W1g[k0 + j];
      ahi[j] = (_Float16)W1g[32 + k0 + j];
      blo[j] = (_Float16)W1g[64 + k0 + j];
      bhi[j] = (_Float16)W1g[96 + k0 + j];
    }
    W1Alo[s] = alo; W1Ahi[s] = ahi; W1Blo[s] = blo; W1Bhi[s] = bhi;
  }
  if (jp == 1 && s < 64) {
    const int col = s & 15;
    const int k0 = (s >> 4) * 8;
    f16x8 wlo, whi;
#pragma unroll
    for (int j = 0; j < 8; ++j) {
      float vlo, vhi;
      if (col < 12) { vlo = Wqg[(k0 + j)*16 + cmapf(col)];  vhi = Wqg[(32 + k0 + j)*16 + cmapf(col)]; }
      else          { vlo = Wpg[(k0 + j)*4 + (col - 12)];   vhi = Wpg[(32 + k0 + j)*4 + (col - 12)]; }
      wlo[j] = (_Float16)vlo; whi[j] = (_Float16)vhi;
    }
    WBlo[s] = wlo; WBhi[s] = whi;
  }
  if (jp == 2 && s < 16) {
    bias16[s] = (s < 12) ? bqg[cmapf(s)] : bpg[s - 12];
  }
}

// block = one v (1024 blocks), thread = one site s (256 threads).
// R12 structure; IEEE div/sqrt replaced by v_rcp/v_rsq (1-ulp, 14x tolerance
// headroom) — removes ~5x10 + 2x8 slow-path instrs per thread per iteration.
__global__ __launch_bounds__(256) void mlme_kernel(
    const float* __restrict__ c1g, const float* __restrict__ c2g,
    const float* __restrict__ lf1g, const float* __restrict__ lf2g,
    const _Float16* __restrict__ U0h,
    const f16x8* __restrict__ W1Alo, const f16x8* __restrict__ W1Ahi,
    const f16x8* __restrict__ W1Blo, const f16x8* __restrict__ W1Bhi,
    const f16x8* __restrict__ WBlo,  const f16x8* __restrict__ WBhi,
    const float* __restrict__ bias16g,
    float* __restrict__ outg)
{
  __shared__ float cLDS[256 * 20];  // 20 KB, per-wave 64-row slabs, stride 20
  __shared__ float sred[24];        // 8 per iteration

  const int v = blockIdx.x;
  const int tid = threadIdx.x;
  const int lane = tid & 63;
  const int wid = tid >> 6;
  const int lane16 = lane & 15;
  const int kgrp = lane >> 4;

  // pinned per-lane fragments (L2-hot, loaded once — R10 proved this tier works)
  const f16x8 w1alo = W1Alo[lane], w1ahi = W1Ahi[lane];
  const f16x8 w1blo = W1Blo[lane], w1bhi = W1Bhi[lane];
  const f16x8 wblo  = WBlo[lane],  wbhi  = WBhi[lane];

  // per-thread (redundant, wave-uniform) per-v setup
  const float c10 = c1g[2*v], c11 = c1g[2*v+1];
  const float c20 = c2g[2*v], c21 = c2g[2*v+1];
  float p0, p1, q0, q1;
  {
    float pn = fsqrt_fast(c10*c10 + c11*c11 + EPSf);
    float qn = fsqrt_fast(c20*c20 + c21*c21 + EPSf);
    p0 = c10; p1 = c11; q0 = c20; q1 = c21;
    if (pn > qn) { float rr = qn * frcp(pn); p0 = c10*rr; p1 = c11*rr; }
    if (qn > pn) { float rr = pn * frcp(qn); q0 = c20*rr; q1 = c21*rr; }
  }
  float alpha = 0.5f, beta = 0.5f;

  // f = exp(log_felsenstein) per thread, once
  float f1[4], f2[4];
  {
    float4 a = reinterpret_cast<const float4*>(lf1g)[v*256 + tid];
    float4 b = reinterpret_cast<const float4*>(lf2g)[v*256 + tid];
    f1[0]=__expf(a.x); f1[1]=__expf(a.y); f1[2]=__expf(a.z); f1[3]=__expf(a.w);
    f2[0]=__expf(b.x); f2[1]=__expf(b.y); f2[2]=__expf(b.z); f2[3]=__expf(b.w);
  }

  const float biasv = bias16g[lane16];   // MFMA C-init (C col = lane16 = feature)

  // A-side u base: row = wid*64 + mt*16 + lane16, k-slice = kgrp*8 (+32 for hi)
  const _Float16* Ubase = U0h + (wid*64 + lane16)*64 + kgrp*8;

  for (int it = 0; it < 3; ++it) {
    const float mid0 = p0*alpha + q0*(1.f-alpha);
    const float mid1 = p1*alpha + q1*(1.f-alpha);
    const float par0 = mid0*beta, par1 = mid1*beta;
    const float d10 = c10-par0, d11 = c11-par1;
    const float d20 = c20-par0, d21 = c21-par1;
    const float t1sq = d10*d10 + d11*d11 + EPSf;
    const float t2sq = d20*d20 + d21*d21 + EPSf;
    const float rst1 = __builtin_amdgcn_rsqf(t1sq);
    const float rst2 = __builtin_amdgcn_rsqf(t2sq);
    const float t1 = t1sq * rst1;   // sqrt via x*rsqrt(x)
    const float t2 = t2sq * rst2;
    const float inv_t1 = rst1;      // 1/t1 = rsqrt(t1sq) exactly what epilogue needs
    const float inv_t2 = rst2;

    // ---- MLP on MFMA: h = relu(u + par0*w1a + par1*w1b) on A-fragments ----
    const _Float16 p0h = (_Float16)par0, p1h = (_Float16)par1;
    const f16x8 p0v = {p0h,p0h,p0h,p0h,p0h,p0h,p0h,p0h};
    const f16x8 p1v = {p1h,p1h,p1h,p1h,p1h,p1h,p1h,p1h};
    const f16x8 z8 = {0,0,0,0,0,0,0,0};
    f32x4 accm[4];
#pragma unroll
    for (int mt = 0; mt < 4; ++mt) {
      accm[mt] = (f32x4){biasv, biasv, biasv, biasv};
      f16x8 ulo = *reinterpret_cast<const f16x8*>(Ubase + mt*16*64);
      f16x8 uhi = *reinterpret_cast<const f16x8*>(Ubase + mt*16*64 + 32);
      f16x8 hlo = __builtin_elementwise_max(
          __builtin_elementwise_fma(p1v, w1blo, __builtin_elementwise_fma(p0v, w1alo, ulo)), z8);
      f16x8 hhi = __builtin_elementwise_max(
          __builtin_elementwise_fma(p1v, w1bhi, __builtin_elementwise_fma(p0v, w1ahi, uhi)), z8);
      accm[mt] = __builtin_amdgcn_mfma_f32_16x16x32_f16(hlo, wblo, accm[mt], 0, 0, 0);
      accm[mt] = __builtin_amdgcn_mfma_f32_16x16x32_f16(hhi, wbhi, accm[mt], 0, 0, 0);
    }
    // transpose C within the wave's own 64-row slab (intra-wave: no block barrier)
#pragma unroll
    for (int mt = 0; mt < 4; ++mt) {
#pragma unroll
      for (int i = 0; i < 4; ++i) {
        cLDS[(wid*64 + mt*16 + kgrp*4 + i)*20 + lane16] = accm[mt][i];
      }
    }
    asm volatile("s_waitcnt lgkmcnt(0)" ::: "memory");
    __builtin_amdgcn_sched_barrier(0);
    float a16[16];
#pragma unroll
    for (int cg = 0; cg < 4; ++cg) {
      f32x4 vv = *reinterpret_cast<const f32x4*>(&cLDS[tid*20 + cg*4]);
#pragma unroll
      for (int i = 0; i < 4; ++i) a16[cg*4 + i] = vv[i];
    }

    // ---- softplus on the 12 off-diagonals; build Q and its 1-norm ----
    float o[12];
#pragma unroll
    for (int k = 0; k < 12; ++k) {
      float xx = a16[k];
      o[k] = fmaxf(xx, 0.f) + __logf(1.f + __expf(-fabsf(xx)));
    }
    const float rs0 = o[0]+o[1]+o[2],  rs1 = o[3]+o[4]+o[5];
    const float rs2 = o[6]+o[7]+o[8],  rs3 = o[9]+o[10]+o[11];
    v2f Qm[8];
    Qm[0] = mkv2(-rs0, o[0]);  Qm[1] = mkv2(o[1], o[2]);
    Qm[2] = mkv2(o[3], -rs1);  Qm[3] = mkv2(o[4], o[5]);
    Qm[4] = mkv2(o[6], o[7]);  Qm[5] = mkv2(-rs2, o[8]);
    Qm[6] = mkv2(o[9], o[10]); Qm[7] = mkv2(o[11], -rs3);
    const float cs0 = rs0 + o[3] + o[6] + o[9];
    const float cs1 = o[0] + rs1 + o[7] + o[10];
    const float cs2 = o[1] + o[4] + rs2 + o[11];
    const float cs3 = o[2] + o[5] + o[8] + rs3;
    const float L1Q = fmaxf(fmaxf(cs0, cs1), fmaxf(cs2, cs3));
    // wave-max of L1Q -> wave-uniform squaring count for both branches
    float Lmax = L1Q;
#pragma unroll
    for (int off = 1; off < 64; off <<= 1)
      Lmax = fmaxf(Lmax, __shfl_xor(Lmax, off, 64));

    // unnormalized stationary probs (normalization cancels in gradient ratio)
    float st[4];
    {
      float mx = fmaxf(fmaxf(a16[12], a16[13]), fmaxf(a16[14], a16[15]));
      st[0]=__expf(a16[12]-mx); st[1]=__expf(a16[13]-mx);
      st[2]=__expf(a16[14]-mx); st[3]=__expf(a16[15]-mx);
    }

    // shared powers
    v2f Q2m[8], Q3m[8], Q4m[8];
    mm4v(Q2m, Qm, Qm);
    mm4v(Q3m, Q2m, Qm);
    mm4v(Q4m, Q2m, Q2m);

    float y1[4], dy1[4], y2[4], dy2[4];
    site_branch(Qm, Q2m, Q3m, Q4m, Lmax, t1, f1, y1, dy1);
    site_branch(Qm, Q2m, Q3m, Q4m, Lmax, t2, f2, y2, dy2);

    // g_k = sum_a dy_k[a] * (other y)[a] * st[a] / sum_a y1 y2 st
    float den = 0.f, num1 = 0.f, num2 = 0.f;
#pragma unroll
    for (int a = 0; a < 4; ++a) {
      float ys2 = y2[a] * st[a];
      den  = fmaf(y1[a],  ys2, den);
      num1 = fmaf(dy1[a], ys2, num1);
      num2 = fmaf(y1[a] * st[a], dy2[a], num2);
    }
    const float invden = frcp(den);
    float g1c = num1 * invden;
    float g2c = num2 * invden;

#pragma unroll
    for (int off = 32; off > 0; off >>= 1) {
      g1c += __shfl_xor(g1c, off, 64);
      g2c += __shfl_xor(g2c, off, 64);
    }
    if (lane == 0) { sred[it*8 + wid*2 + 0] = g1c; sred[it*8 + wid*2 + 1] = g2c; }
    __syncthreads();
    // all threads compute the (identical) update redundantly
    {
      float g1 = sred[it*8+0]+sred[it*8+2]+sred[it*8+4]+sred[it*8+6];
      float g2 = sred[it*8+1]+sred[it*8+3]+sred[it*8+5]+sred[it*8+7];
      float db1da = ((par0-c10)*(p0-q0) + (par1-c11)*(p1-q1)) * beta * inv_t1;
      float db2da = ((par0-c20)*(p0-q0) + (par1-c21)*(p1-q1)) * beta * inv_t2;
      float db1db = ((par0-c10)*mid0 + (par1-c11)*mid1) * inv_t1;
      float db2db = ((par0-c20)*mid0 + (par1-c21)*mid1) * inv_t2;
      float ga = g1*db1da + g2*db2da;
      float gb = g1*db1db + g2*db2db;
      ga = fminf(1.f, fmaxf(-1.f, ga));
      gb = fminf(1.f, fmaxf(-1.f, gb));
      alpha = fminf(1.f, fmaxf(0.f, alpha + 0.1f*ga));
      beta  = fminf(1.f, fmaxf(0.f, beta  + 0.1f*gb));
    }
  }

  if (tid == 0) {
    float m0 = p0*alpha + q0*(1.f-alpha);
    float m1 = p1*alpha + q1*(1.f-alpha);
    outg[2*v]   = m0*beta;
    outg[2*v+1] = m1*beta;
  }
}

extern "C" void kernel_launch(void* const* d_in, const int* in_sizes, int n_in,
                              void* d_out, int out_size, void* d_ws, size_t ws_size,
                              hipStream_t stream) {
  (void)in_sizes; (void)n_in; (void)ws_size; (void)out_size;
  const float* c1  = (const float*)d_in[0];
  const float* c2  = (const float*)d_in[1];
  const float* lf1 = (const float*)d_in[2];
  const float* lf2 = (const float*)d_in[3];
  const float* sp  = (const float*)d_in[4];
  const float* W1  = (const float*)d_in[5];
  const float* b1  = (const float*)d_in[6];
  const float* Wq  = (const float*)d_in[7];
  const float* bq  = (const float*)d_in[8];
  const float* Wp  = (const float*)d_in[9];
  const float* bp  = (const float*)d_in[10];
  float* out = (float*)d_out;

  char* ws = (char*)d_ws;
  _Float16* U0h   = (_Float16*)ws;                 // 256*64*2 = 32768 B
  f16x8* W1Alo = (f16x8*)(ws + 32768);             // 64*16 = 1024 B
  f16x8* W1Ahi = (f16x8*)(ws + 33792);
  f16x8* W1Blo = (f16x8*)(ws + 34816);
  f16x8* W1Bhi = (f16x8*)(ws + 35840);
  f16x8* WBlo  = (f16x8*)(ws + 36864);
  f16x8* WBhi  = (f16x8*)(ws + 37888);
  float* bias16 = (float*)(ws + 38912);            // 64 B

  prep_kernel<<<dim3(32), dim3(256), 0, stream>>>(sp, W1, b1, Wq, bq, Wp, bp,
                                                  U0h, W1Alo, W1Ahi, W1Blo, W1Bhi,
                                                  WBlo, WBhi, bias16);
  mlme_kernel<<<dim3(1024), dim3(256), 0, stream>>>(
      c1, c2, lf1, lf2, U0h, W1Alo, W1Ahi, W1Blo, W1Bhi, WBlo, WBhi, bias16, out);
}